// Round 2
// baseline (545.854 us; speedup 1.0000x reference)
//
#include <hip/hip_runtime.h>

// Problem UIGen_63058709840320: I=32000, L=2048, D=256.
// Algebraic collapse: out = (weighted[L-2] + weighted[L-1]) @ D2; only rows
// L-2, L-1 of posEmbed/dense1/attention are ever needed.
//
// v3: ONE fused kernel (plus a 1.2 KB flag-clear memset). Roles by blockIdx:
//   [0,250)    rows : x rows @ DE -> per-block partials (plain stores), flag.
//   [250,266)  mid  : poll rows flags -> dense1 k-chunk contribs mpart[16][512],
//                     flag; poll mid flags -> attention contribs apart[16][512],
//                     flag. No atomics anywhere -> no zero-init of accumulators.
//   [266,516)  out  : poll att flags -> s[d] = da*ta + db*tb via 16-way reduce
//                     of mpart/apart, then stream D2 (32 float4 cols/block),
//                     LDS d-reduce, plain float4 stores.
// Sync: device-scope release/acquire flags in ws; all 516 blocks co-resident
// (516*256 threads << 256 CU * 2048). Flags cleared by a tiny memset so
// correctness does not depend on the harness's 0xAA poison.
namespace {
constexpr int LL = 2048;
constexpr int II = 32000;
constexpr int DD = 256;
constexpr int NR = 250;   // rows blocks (128 i's each)
constexpr int NM = 16;    // mid blocks (32-wide k-chunks of the 512 concat dim)
constexpr int NO = 250;   // out blocks (32 float4 i-columns each; 250*32 = 8000)
constexpr unsigned MAGIC = 0x5A17ED99u;

// ws float layout:
//   part  [0, NR*512)            rows partials [blk][row0 d | row1 d]
//   mpart [NR*512, +NM*512)      dense1 chunk contributions
//   apart [..,   +NM*512)        attention chunk contributions
//   flags (unsigned)             done0[256-pad] | done1[16] | done2[16]
constexpr int OFF_MPART = NR * 512;
constexpr int OFF_APART = OFF_MPART + NM * 512;
constexpr int OFF_FLAGS = OFF_APART + NM * 512;   // float offset; 16B aligned
constexpr int N_FLAGS = 256 + 16 + 16;            // 1152 bytes

__device__ __forceinline__ void publish(unsigned* f) {
  // All data stores of the block happen-before this: each thread fenced, then
  // __syncthreads, then t0 release-stores the flag.
  __hip_atomic_store(f, MAGIC, __ATOMIC_RELEASE, __HIP_MEMORY_SCOPE_AGENT);
}

__device__ __forceinline__ void wait_flags(unsigned* flags, int n, int t) {
  for (;;) {
    bool ok = true;
    if (t < n)
      ok = (__hip_atomic_load(&flags[t], __ATOMIC_ACQUIRE,
                              __HIP_MEMORY_SCOPE_AGENT) == MAGIC);
    if (__syncthreads_and(ok)) break;
    __builtin_amdgcn_s_sleep(8);  // ~512 cycles between polls
  }
}

__global__ __launch_bounds__(256) void k_fused(
    const float* __restrict__ x, const float* __restrict__ DE,
    const float* __restrict__ PE, const float* __restrict__ D1,
    const float* __restrict__ Att, const float* __restrict__ D2,
    float* __restrict__ ws, float* __restrict__ out) {
  float* part = ws;
  float* mpart = ws + OFF_MPART;
  float* apart = ws + OFF_APART;
  unsigned* flags = reinterpret_cast<unsigned*>(ws + OFF_FLAGS);
  unsigned* done0 = flags;
  unsigned* done1 = flags + 256;
  unsigned* done2 = flags + 256 + 16;

  const int t = threadIdx.x;
  const int bid = blockIdx.x;

  if (bid < NR) {
    // ---------------- rows role: partials of x[L-2]@DE, x[L-1]@DE ----------
    const int lane = t & 63;  // float4 group within D (64*4 = 256)
    const int sub = t >> 6;   // 0..3, i interleave
    const float4* __restrict__ DE4 = reinterpret_cast<const float4*>(DE);
    const float* __restrict__ x0 = x + (size_t)(LL - 2) * II;
    const float* __restrict__ x1 = x + (size_t)(LL - 1) * II;
    const int i0 = bid * 128;
    float4 a0 = {0.f, 0.f, 0.f, 0.f};
    float4 a1 = {0.f, 0.f, 0.f, 0.f};
#pragma unroll 8
    for (int ii = 0; ii < 32; ++ii) {
      const int i = i0 + sub + 4 * ii;
      const float4 de = DE4[(size_t)i * (DD / 4) + lane];
      const float s0 = x0[i];
      const float s1 = x1[i];
      a0.x = fmaf(s0, de.x, a0.x);
      a0.y = fmaf(s0, de.y, a0.y);
      a0.z = fmaf(s0, de.z, a0.z);
      a0.w = fmaf(s0, de.w, a0.w);
      a1.x = fmaf(s1, de.x, a1.x);
      a1.y = fmaf(s1, de.y, a1.y);
      a1.z = fmaf(s1, de.z, a1.z);
      a1.w = fmaf(s1, de.w, a1.w);
    }
    __shared__ float red[8][DD];  // [sub*2 + row][d]
    {
      float* r0 = &red[sub * 2 + 0][lane * 4];
      r0[0] = a0.x; r0[1] = a0.y; r0[2] = a0.z; r0[3] = a0.w;
      float* r1 = &red[sub * 2 + 1][lane * 4];
      r1[0] = a1.x; r1[1] = a1.y; r1[2] = a1.z; r1[3] = a1.w;
    }
    __syncthreads();
    float* p = part + (size_t)bid * 512;
    p[t] = red[0][t] + red[2][t] + red[4][t] + red[6][t];
    p[DD + t] = red[1][t] + red[3][t] + red[5][t] + red[7][t];
    __threadfence();
    __syncthreads();
    if (t == 0) publish(&done0[bid]);

  } else if (bid < NR + NM) {
    // ---------------- mid role: dense1 then attention chunk contribs -------
    const int m = bid - NR;
    const int k0 = m * 32;                       // concat-dim chunk base
    const int j0 = (k0 < DD) ? k0 : (k0 - DD);   // d-slice it maps to
    wait_flags(done0, NR, t);

    // Phase M1: reduce rows partials for own j-slice, build dense1 input
    // slice (pool1 is elementwise: pool1[L-2]=(a+b)/2047, pool1[L-1]=b/2048),
    // multiply by own D1 rows -> mpart[m].
    __shared__ float reda[8][32], redb[8][32];
    __shared__ float va[32], vb[32];
    {
      const int jj = t & 31;
      const int pp = t >> 5;
      float sa = 0.f, sb = 0.f;
      for (int p = pp; p < NR; p += 8) {
        const float* pr = part + (size_t)p * 512 + j0 + jj;
        sa += pr[0];
        sb += pr[DD];
      }
      reda[pp][jj] = sa;
      redb[pp][jj] = sb;
    }
    __syncthreads();
    if (t < 32) {
      float a = PE[(size_t)(LL - 2) * DD + j0 + t];
      float b = PE[(size_t)(LL - 1) * DD + j0 + t];
#pragma unroll
      for (int q = 0; q < 8; ++q) {
        a += reda[q][t];
        b += redb[q][t];
      }
      if (k0 < DD) {
        va[t] = a;
        vb[t] = b;
      } else {
        va[t] = (a + b) * (1.0f / (float)(LL - 1));
        vb[t] = b * (1.0f / (float)LL);
      }
    }
    __syncthreads();
    {
      float ra = 0.f, rb = 0.f;
#pragma unroll 8
      for (int kk = 0; kk < 32; ++kk) {
        const float w = D1[(size_t)(k0 + kk) * DD + t];
        ra = fmaf(va[kk], w, ra);
        rb = fmaf(vb[kk], w, rb);
      }
      mpart[(size_t)m * 512 + t] = ra;
      mpart[(size_t)m * 512 + DD + t] = rb;
    }
    __threadfence();
    __syncthreads();
    if (t == 0) publish(&done1[m]);

    // Phase M2: dense1 values at own slice via 16-way mpart reduce, pool2
    // scaling, multiply by own Att rows -> apart[m].
    wait_flags(done1, NM, t);
    __shared__ float wa[32], wb[32];
    if (t < 32) {
      float da = 0.f, db = 0.f;
#pragma unroll
      for (int q = 0; q < NM; ++q) {
        da += mpart[(size_t)q * 512 + j0 + t];
        db += mpart[(size_t)q * 512 + DD + j0 + t];
      }
      if (k0 < DD) {
        wa[t] = da;
        wb[t] = db;
      } else {
        wa[t] = (da + db) * (1.0f / (float)(LL - 1));
        wb[t] = db * (1.0f / (float)LL);
      }
    }
    __syncthreads();
    {
      float ta = 0.f, tb = 0.f;
#pragma unroll 8
      for (int kk = 0; kk < 32; ++kk) {
        const float w = Att[(size_t)(k0 + kk) * DD + t];
        ta = fmaf(wa[kk], w, ta);
        tb = fmaf(wb[kk], w, tb);
      }
      apart[(size_t)m * 512 + t] = ta;
      apart[(size_t)m * 512 + DD + t] = tb;
    }
    __threadfence();
    __syncthreads();
    if (t == 0) publish(&done2[m]);

  } else {
    // ---------------- out role: s[d] then out = s @ D2 ---------------------
    const int ob = bid - NR - NM;
    wait_flags(done2, NM, t);
    __shared__ float sv[DD];
    {
      float da = 0.f, db = 0.f, ta = 0.f, tb = 0.f;
#pragma unroll
      for (int q = 0; q < NM; ++q) {
        const float* mp = mpart + (size_t)q * 512;
        const float* ap = apart + (size_t)q * 512;
        da += mp[t];
        db += mp[DD + t];
        ta += ap[t];
        tb += ap[DD + t];
      }
      sv[t] = fmaf(da, ta, db * tb);  // weighted[L-2]+weighted[L-1] at d=t
    }
    __syncthreads();
    const int l5 = t & 31;  // i4 within block's 32 columns
    const int s3 = t >> 5;  // 0..7, 32-wide d-chunk
    const int i4 = ob * 32 + l5;
    const float4* __restrict__ D24 = reinterpret_cast<const float4*>(D2);
    float4 a = {0.f, 0.f, 0.f, 0.f};
#pragma unroll 8
    for (int k = 0; k < 32; ++k) {
      const int d = s3 * 32 + k;
      const float4 v = D24[(size_t)d * (II / 4) + i4];
      const float sk = sv[d];
      a.x = fmaf(sk, v.x, a.x);
      a.y = fmaf(sk, v.y, a.y);
      a.z = fmaf(sk, v.z, a.z);
      a.w = fmaf(sk, v.w, a.w);
    }
    __shared__ float4 redo[8][32];
    redo[s3][l5] = a;
    __syncthreads();
    if (t < 32) {
      float4 o = {0.f, 0.f, 0.f, 0.f};
#pragma unroll
      for (int q = 0; q < 8; ++q) {
        const float4 r = redo[q][t];
        o.x += r.x;
        o.y += r.y;
        o.z += r.z;
        o.w += r.w;
      }
      reinterpret_cast<float4*>(out)[(size_t)ob * 32 + t] = o;
    }
  }
}

}  // namespace

extern "C" void kernel_launch(void* const* d_in, const int* in_sizes, int n_in,
                              void* d_out, int out_size, void* d_ws, size_t ws_size,
                              hipStream_t stream) {
  (void)in_sizes; (void)n_in; (void)ws_size; (void)out_size;
  const float* x   = (const float*)d_in[0];  // [L, I]
  const float* DE  = (const float*)d_in[1];  // [I, D]
  const float* PE  = (const float*)d_in[2];  // [L, D]
  const float* D1  = (const float*)d_in[3];  // [2D, D]
  const float* D2  = (const float*)d_in[4];  // [D, I]
  const float* Att = (const float*)d_in[5];  // [2D, D]
  float* out = (float*)d_out;                // [1, I] fp32
  float* ws = (float*)d_ws;

  // Clear only the 1152-byte flag region: correctness then never depends on
  // the harness's 0xAA poison semantics. Everything else in ws is written
  // before it is read.
  hipMemsetAsync(ws + OFF_FLAGS, 0, N_FLAGS * sizeof(unsigned), stream);

  k_fused<<<NR + NM + NO, 256, 0, stream>>>(x, DE, PE, D1, Att, D2, ws, out);
}

// Round 4
// 370.752 us; speedup vs baseline: 1.4723x; 1.4723x over previous
//
#include <hip/hip_runtime.h>

// Problem UIGen_63058709840320: I=32000, L=2048, D=256.
// Algebraic collapse: out = (weighted[L-2] + weighted[L-1]) @ D2; only rows
// L-2, L-1 of posEmbed/dense1/attention are ever needed.
//
// v4b: ONE fused kernel, fixed sync protocol (v3's 18x slowdown was caused by
// acquire-loads in the spin loops: every agent-scope acquire emits buffer_inv,
// so ~500 spinning waves invalidated L2 continuously while rows blocks tried
// to stream DE).
//   - spin with RELAXED agent loads (no invalidate per poll), then ONE
//     acquire fence (__builtin_amdgcn_fence agent) per phase once flags seen.
//   - publish: __syncthreads() (compiler drains vmcnt before s_barrier) then
//     a single t0 release store (one L2 writeback per block, not 4/wave).
//   - out role merged into rows blocks: grid 266 = 250 rows+out | 16 mid.
//     Nobody idles during the DE-streaming phase; only 16 blocks poll then.
// Roles:
//   [0,250)   rows+out : x rows @ DE -> per-block partials (plain stores),
//             publish done0[b]; wait done2; s[d] = da*ta+db*tb via 16-way
//             mpart/apart reduce; stream D2 (32 float4 cols), LDS d-reduce,
//             plain float4 stores.
//   [250,266) mid : wait done0 -> dense1 k-chunk contribs mpart[m] -> done1;
//             wait done1 -> attention contribs apart[m] -> done2.
namespace {
constexpr int LL = 2048;
constexpr int II = 32000;
constexpr int DD = 256;
constexpr int NR = 250;   // rows+out blocks (128 i's each; 32 float4 cols each)
constexpr int NM = 16;    // mid blocks (32-wide k-chunks of the 512 concat dim)
constexpr unsigned MAGIC = 0x5A17ED99u;

// ws float layout:
//   part  [0, NR*512)          rows partials [blk][row0 d | row1 d]
//   mpart [NR*512, +NM*512)    dense1 chunk contributions
//   apart [..,   +NM*512)      attention chunk contributions
//   flags (unsigned)           done0[256-pad] | done1[16] | done2[16]
constexpr int OFF_MPART = NR * 512;
constexpr int OFF_APART = OFF_MPART + NM * 512;
constexpr int OFF_FLAGS = OFF_APART + NM * 512;   // float offset; 16B aligned
constexpr int N_FLAGS = 256 + 16 + 16;            // 1152 bytes

__device__ __forceinline__ void publish(unsigned* f) {
  // Caller guarantees __syncthreads() immediately before (drains the block's
  // stores into L2); release store writes back L2 once and sets the flag at
  // the coherence point.
  __hip_atomic_store(f, MAGIC, __ATOMIC_RELEASE, __HIP_MEMORY_SCOPE_AGENT);
}

// Spin on flags[0..n) == MAGIC with RELAXED loads (no buffer_inv per poll).
// One acquire fence after observation orders the subsequent data reads.
template <int SLP>
__device__ __forceinline__ void wait_flags(const unsigned* flags, int n,
                                           int t) {
  for (;;) {
    bool ok = true;
    if (t < n)
      ok = (__hip_atomic_load(&flags[t], __ATOMIC_RELAXED,
                              __HIP_MEMORY_SCOPE_AGENT) == MAGIC);
    if (__syncthreads_and(ok)) break;
    __builtin_amdgcn_s_sleep(SLP);
  }
  __builtin_amdgcn_fence(__ATOMIC_ACQUIRE, "agent");
}

__global__ __launch_bounds__(256) void k_fused(
    const float* __restrict__ x, const float* __restrict__ DE,
    const float* __restrict__ PE, const float* __restrict__ D1,
    const float* __restrict__ Att, const float* __restrict__ D2,
    float* __restrict__ ws, float* __restrict__ out) {
  float* part = ws;
  float* mpart = ws + OFF_MPART;
  float* apart = ws + OFF_APART;
  unsigned* flags = reinterpret_cast<unsigned*>(ws + OFF_FLAGS);
  unsigned* done0 = flags;
  unsigned* done1 = flags + 256;
  unsigned* done2 = flags + 256 + 16;

  const int t = threadIdx.x;
  const int bid = blockIdx.x;

  if (bid < NR) {
    // ---------------- rows phase: partials of x[L-2]@DE, x[L-1]@DE ---------
    const int lane = t & 63;  // float4 group within D (64*4 = 256)
    const int sub = t >> 6;   // 0..3, i interleave
    const float4* __restrict__ DE4 = reinterpret_cast<const float4*>(DE);
    const float* __restrict__ x0 = x + (size_t)(LL - 2) * II;
    const float* __restrict__ x1 = x + (size_t)(LL - 1) * II;
    const int i0 = bid * 128;
    float4 a0 = {0.f, 0.f, 0.f, 0.f};
    float4 a1 = {0.f, 0.f, 0.f, 0.f};
#pragma unroll 8
    for (int ii = 0; ii < 32; ++ii) {
      const int i = i0 + sub + 4 * ii;
      const float4 de = DE4[(size_t)i * (DD / 4) + lane];
      const float s0 = x0[i];
      const float s1 = x1[i];
      a0.x = fmaf(s0, de.x, a0.x);
      a0.y = fmaf(s0, de.y, a0.y);
      a0.z = fmaf(s0, de.z, a0.z);
      a0.w = fmaf(s0, de.w, a0.w);
      a1.x = fmaf(s1, de.x, a1.x);
      a1.y = fmaf(s1, de.y, a1.y);
      a1.z = fmaf(s1, de.z, a1.z);
      a1.w = fmaf(s1, de.w, a1.w);
    }
    __shared__ float red[8][DD];  // [sub*2 + row][d]
    {
      float* r0 = &red[sub * 2 + 0][lane * 4];
      r0[0] = a0.x; r0[1] = a0.y; r0[2] = a0.z; r0[3] = a0.w;
      float* r1 = &red[sub * 2 + 1][lane * 4];
      r1[0] = a1.x; r1[1] = a1.y; r1[2] = a1.z; r1[3] = a1.w;
    }
    __syncthreads();
    float* p = part + (size_t)bid * 512;
    p[t] = red[0][t] + red[2][t] + red[4][t] + red[6][t];
    p[DD + t] = red[1][t] + red[3][t] + red[5][t] + red[7][t];
    __syncthreads();  // drains the partial stores (vmcnt) before the release
    if (t == 0) publish(&done0[bid]);

    // ---------------- out phase: wait mid, s[d], out = s @ D2 --------------
    wait_flags<16>(done2, NM, t);
    __shared__ float sv[DD];
    {
      float da = 0.f, db = 0.f, ta = 0.f, tb = 0.f;
#pragma unroll
      for (int q = 0; q < NM; ++q) {
        const float* mp = mpart + (size_t)q * 512;
        const float* ap = apart + (size_t)q * 512;
        da += mp[t];
        db += mp[DD + t];
        ta += ap[t];
        tb += ap[DD + t];
      }
      sv[t] = fmaf(da, ta, db * tb);  // weighted[L-2]+weighted[L-1] at d=t
    }
    __syncthreads();
    const int l5 = t & 31;  // i4 within block's 32 columns
    const int s3 = t >> 5;  // 0..7, 32-wide d-chunk
    const int i4 = bid * 32 + l5;
    const float4* __restrict__ D24 = reinterpret_cast<const float4*>(D2);
    float4 a = {0.f, 0.f, 0.f, 0.f};
#pragma unroll 8
    for (int k = 0; k < 32; ++k) {
      const int d = s3 * 32 + k;
      const float4 v = D24[(size_t)d * (II / 4) + i4];
      const float sk = sv[d];
      a.x = fmaf(sk, v.x, a.x);
      a.y = fmaf(sk, v.y, a.y);
      a.z = fmaf(sk, v.z, a.z);
      a.w = fmaf(sk, v.w, a.w);
    }
    __shared__ float4 redo[8][32];
    redo[s3][l5] = a;
    __syncthreads();
    if (t < 32) {
      float4 o = {0.f, 0.f, 0.f, 0.f};
#pragma unroll
      for (int q = 0; q < 8; ++q) {
        const float4 r = redo[q][t];
        o.x += r.x;
        o.y += r.y;
        o.z += r.z;
        o.w += r.w;
      }
      reinterpret_cast<float4*>(out)[(size_t)bid * 32 + t] = o;
    }

  } else {
    // ---------------- mid role: dense1 then attention chunk contribs -------
    const int m = bid - NR;
    const int k0 = m * 32;                       // concat-dim chunk base
    const int j0 = (k0 < DD) ? k0 : (k0 - DD);   // d-slice it maps to
    wait_flags<64>(done0, NR, t);

    // Phase M1: reduce rows partials for own j-slice, build dense1 input
    // slice (pool1 is elementwise: pool1[L-2]=(a+b)/2047, pool1[L-1]=b/2048),
    // multiply by own D1 rows -> mpart[m].
    __shared__ float reda[8][32], redb[8][32];
    __shared__ float va[32], vb[32];
    {
      const int jj = t & 31;
      const int pp = t >> 5;
      float sa = 0.f, sb = 0.f;
      for (int p = pp; p < NR; p += 8) {
        const float* pr = part + (size_t)p * 512 + j0 + jj;
        sa += pr[0];
        sb += pr[DD];
      }
      reda[pp][jj] = sa;
      redb[pp][jj] = sb;
    }
    __syncthreads();
    if (t < 32) {
      float a = PE[(size_t)(LL - 2) * DD + j0 + t];
      float b = PE[(size_t)(LL - 1) * DD + j0 + t];
#pragma unroll
      for (int q = 0; q < 8; ++q) {
        a += reda[q][t];
        b += redb[q][t];
      }
      if (k0 < DD) {
        va[t] = a;
        vb[t] = b;
      } else {
        va[t] = (a + b) * (1.0f / (float)(LL - 1));
        vb[t] = b * (1.0f / (float)LL);
      }
    }
    __syncthreads();
    {
      float ra = 0.f, rb = 0.f;
#pragma unroll 8
      for (int kk = 0; kk < 32; ++kk) {
        const float w = D1[(size_t)(k0 + kk) * DD + t];
        ra = fmaf(va[kk], w, ra);
        rb = fmaf(vb[kk], w, rb);
      }
      mpart[(size_t)m * 512 + t] = ra;
      mpart[(size_t)m * 512 + DD + t] = rb;
    }
    __syncthreads();
    if (t == 0) publish(&done1[m]);

    // Phase M2: dense1 values at own slice via 16-way mpart reduce, pool2
    // scaling, multiply by own Att rows -> apart[m].
    wait_flags<4>(done1, NM, t);
    __shared__ float wa[32], wb[32];
    if (t < 32) {
      float da = 0.f, db = 0.f;
#pragma unroll
      for (int q = 0; q < NM; ++q) {
        da += mpart[(size_t)q * 512 + j0 + t];
        db += mpart[(size_t)q * 512 + DD + j0 + t];
      }
      if (k0 < DD) {
        wa[t] = da;
        wb[t] = db;
      } else {
        wa[t] = (da + db) * (1.0f / (float)(LL - 1));
        wb[t] = db * (1.0f / (float)LL);
      }
    }
    __syncthreads();
    {
      float ta = 0.f, tb = 0.f;
#pragma unroll 8
      for (int kk = 0; kk < 32; ++kk) {
        const float w = Att[(size_t)(k0 + kk) * DD + t];
        ta = fmaf(wa[kk], w, ta);
        tb = fmaf(wb[kk], w, tb);
      }
      apart[(size_t)m * 512 + t] = ta;
      apart[(size_t)m * 512 + DD + t] = tb;
    }
    __syncthreads();
    if (t == 0) publish(&done2[m]);
  }
}

}  // namespace

extern "C" void kernel_launch(void* const* d_in, const int* in_sizes, int n_in,
                              void* d_out, int out_size, void* d_ws, size_t ws_size,
                              hipStream_t stream) {
  (void)in_sizes; (void)n_in; (void)ws_size; (void)out_size;
  const float* x   = (const float*)d_in[0];  // [L, I]
  const float* DE  = (const float*)d_in[1];  // [I, D]
  const float* PE  = (const float*)d_in[2];  // [L, D]
  const float* D1  = (const float*)d_in[3];  // [2D, D]
  const float* D2  = (const float*)d_in[4];  // [D, I]
  const float* Att = (const float*)d_in[5];  // [2D, D]
  float* out = (float*)d_out;                // [1, I] fp32
  float* ws = (float*)d_ws;

  // Clear only the 1152-byte flag region: correctness never depends on the
  // harness's 0xAA poison semantics. Everything else in ws is written before
  // it is read.
  (void)hipMemsetAsync(ws + OFF_FLAGS, 0, N_FLAGS * sizeof(unsigned), stream);

  k_fused<<<NR + NM, 256, 0, stream>>>(x, DE, PE, D1, Att, D2, ws, out);
}